// Round 4
// baseline (386.001 us; speedup 1.0000x reference)
//
#include <hip/hip_runtime.h>
#include <hip/hip_bf16.h>

#define B_ 8
#define T_ 2048
#define C_ 1024
#define H_ 128

typedef __bf16 bf16x8 __attribute__((ext_vector_type(8)));
typedef float f32x4 __attribute__((ext_vector_type(4)));

static __device__ __forceinline__ bf16x8 cvt8(float4 a, float4 b) {
    bf16x8 r;
    r[0] = (__bf16)a.x; r[1] = (__bf16)a.y; r[2] = (__bf16)a.z; r[3] = (__bf16)a.w;
    r[4] = (__bf16)b.x; r[5] = (__bf16)b.y; r[6] = (__bf16)b.z; r[7] = (__bf16)b.w;
    return r;
}

// ---------------------------------------------------------------------------
// Projection: out = x @ W^T for Wq, Wk, Wv.
// One wave per block; wave computes a 16-row x 128-col tile for one weight.
// A-frag (x): row = lane&15, k = (lane>>4)*8 + i   (contiguous 8, fp32->bf16)
// B-frag (W): col(h) = lane&15, k = (lane>>4)*8+i  -> W[h][k..k+7] contiguous
// D: col(h) = lane&15, row = (lane>>4)*4 + r       (m89-verified layout)
// q,k stored [B][T][H] bf16; v stored transposed [B][H][T] bf16 for PV frags.
// ---------------------------------------------------------------------------
__global__ __launch_bounds__(64) void proj_kernel(
    const float* __restrict__ x,
    const float* __restrict__ Wq, const float* __restrict__ Wk,
    const float* __restrict__ Wv,
    __bf16* __restrict__ qb, __bf16* __restrict__ kb, __bf16* __restrict__ vTb)
{
    const int lane = threadIdx.x;
    const int gw = blockIdx.x;            // 0..3071
    const int which = gw >> 10;           // 0=q, 1=k, 2=v
    const int mt = gw & 1023;             // 16-row tile over M = B*T = 16384

    const float* W = (which == 0) ? Wq : (which == 1) ? Wk : Wv;

    const int fr = lane & 15;
    const int koff = (lane >> 4) * 8;

    const float* xrow = x + (size_t)(mt * 16 + fr) * C_ + koff;
    const float* wbase = W + (size_t)fr * C_ + koff;

    f32x4 acc[8];
#pragma unroll
    for (int i = 0; i < 8; i++) acc[i] = (f32x4){0.f, 0.f, 0.f, 0.f};

    for (int kc = 0; kc < C_; kc += 32) {
        float4 xa = *(const float4*)(xrow + kc);
        float4 xb = *(const float4*)(xrow + kc + 4);
        bf16x8 af = cvt8(xa, xb);
#pragma unroll
        for (int ht = 0; ht < 8; ht++) {
            const float* wrow = wbase + (size_t)ht * 16 * C_ + kc;
            float4 wa = *(const float4*)(wrow);
            float4 wb = *(const float4*)(wrow + 4);
            bf16x8 bfr = cvt8(wa, wb);
            acc[ht] = __builtin_amdgcn_mfma_f32_16x16x32_bf16(af, bfr, acc[ht], 0, 0, 0);
        }
    }

    const int rbase = (lane >> 4) * 4;
#pragma unroll
    for (int ht = 0; ht < 8; ht++) {
#pragma unroll
        for (int r = 0; r < 4; r++) {
            int row = mt * 16 + rbase + r;          // global row = b*T + t
            int h = ht * 16 + fr;
            __bf16 val = (__bf16)acc[ht][r];
            if (which == 0) {
                qb[(size_t)row * H_ + h] = val;
            } else if (which == 1) {
                kb[(size_t)row * H_ + h] = val;
            } else {
                int bb = row >> 11;                  // T_ = 2048
                int tt = row & (T_ - 1);
                vTb[((size_t)bb * H_ + h) * T_ + tt] = val;
            }
        }
    }
}

// ---------------------------------------------------------------------------
// Flash attention, causal. One wave per block; wave owns 16 q-rows, iterates
// KV in tiles of 32 with online softmax (fp32 stats, bf16 P).
// S-tile D-layout: col(key) = lane&15, row(query) = (lane>>4)*4 + r.
// Row reductions via __shfl_xor across the 16-lane group.
// P is redistributed D-layout -> A-layout through a small LDS buffer.
// ---------------------------------------------------------------------------
__global__ __launch_bounds__(64) void attn_kernel(
    const __bf16* __restrict__ qb, const __bf16* __restrict__ kb,
    const __bf16* __restrict__ vTb, float* __restrict__ out)
{
    __shared__ __bf16 plds[16][32];

    const int lane = threadIdx.x;
    const int gw = blockIdx.x;          // 0..1023
    const int b = gw >> 7;
    const int qt = gw & 127;
    const int q0 = qt * 16;

    const int fr = lane & 15;
    const int koff = (lane >> 4) * 8;
    const int rbase = (lane >> 4) * 4;

    // Q fragments for the whole kernel: 4 chunks of K=32 over H=128
    const __bf16* Qbase = qb + ((size_t)b * T_ + q0 + fr) * H_ + koff;
    bf16x8 qf[4];
#pragma unroll
    for (int hc = 0; hc < 4; hc++)
        qf[hc] = *(const bf16x8*)(Qbase + hc * 32);

    float m[4], l[4];
    f32x4 acc[8];
#pragma unroll
    for (int r = 0; r < 4; r++) { m[r] = -1e30f; l[r] = 0.f; }
#pragma unroll
    for (int i = 0; i < 8; i++) acc[i] = (f32x4){0.f, 0.f, 0.f, 0.f};

    const int nkt = (q0 + 15) / 32 + 1;   // causal: tiles with k0 <= q0+15
    const float scale = 0.03125f;          // 1024^-0.5

    for (int kt = 0; kt < nkt; kt++) {
        const int k0 = kt * 32;

        // --- S = Q K^T over 32 keys (two 16-key halves) ---
        f32x4 s0 = (f32x4){0.f, 0.f, 0.f, 0.f};
        f32x4 s1 = (f32x4){0.f, 0.f, 0.f, 0.f};
        const __bf16* Kb0 = kb + ((size_t)b * T_ + k0 + fr) * H_ + koff;
        const __bf16* Kb1 = Kb0 + 16 * H_;
#pragma unroll
        for (int hc = 0; hc < 4; hc++) {
            bf16x8 kf0 = *(const bf16x8*)(Kb0 + hc * 32);
            s0 = __builtin_amdgcn_mfma_f32_16x16x32_bf16(qf[hc], kf0, s0, 0, 0, 0);
            bf16x8 kf1 = *(const bf16x8*)(Kb1 + hc * 32);
            s1 = __builtin_amdgcn_mfma_f32_16x16x32_bf16(qf[hc], kf1, s1, 0, 0, 0);
        }

        // --- scale + causal mask + online softmax stats (fp32) ---
#pragma unroll
        for (int r = 0; r < 4; r++) {
            const int qrow = q0 + rbase + r;
            float v0 = s0[r] * scale;
            float v1 = s1[r] * scale;
            if (k0 + fr > qrow)      v0 = -1e30f;
            if (k0 + 16 + fr > qrow) v1 = -1e30f;

            float mx = fmaxf(v0, v1);
#pragma unroll
            for (int d = 1; d < 16; d <<= 1) mx = fmaxf(mx, __shfl_xor(mx, d));
            const float mnew = fmaxf(m[r], mx);
            const float corr = __expf(m[r] - mnew);
            const float e0 = __expf(v0 - mnew);
            const float e1 = __expf(v1 - mnew);
            float rs = e0 + e1;
#pragma unroll
            for (int d = 1; d < 16; d <<= 1) rs += __shfl_xor(rs, d);
            l[r] = l[r] * corr + rs;
            m[r] = mnew;
#pragma unroll
            for (int ht = 0; ht < 8; ht++) acc[ht][r] *= corr;

            plds[rbase + r][fr] = (__bf16)e0;
            plds[rbase + r][16 + fr] = (__bf16)e1;
        }
        __syncthreads();   // single wave: cheap; orders LDS write->read

        // --- P A-frag: row(query)=lane&15, k(key)=(lane>>4)*8+i ---
        bf16x8 pa = *(const bf16x8*)(&plds[fr][koff]);

        // --- O += P V : B-frag from vT[h][k] contiguous ---
        const __bf16* Vb = vTb + ((size_t)b * H_ + fr) * T_ + k0 + koff;
#pragma unroll
        for (int ht = 0; ht < 8; ht++) {
            bf16x8 vf = *(const bf16x8*)(Vb + (size_t)ht * 16 * T_);
            acc[ht] = __builtin_amdgcn_mfma_f32_16x16x32_bf16(pa, vf, acc[ht], 0, 0, 0);
        }
        __syncthreads();   // protect LDS WAR before next tile
    }

    // --- epilogue: divide by l, write fp32 out[b][t][h] ---
    float inv[4];
#pragma unroll
    for (int r = 0; r < 4; r++) inv[r] = 1.0f / l[r];
    float* obase = out + ((size_t)b * T_ + q0 + rbase) * H_ + fr;
#pragma unroll
    for (int ht = 0; ht < 8; ht++) {
#pragma unroll
        for (int r = 0; r < 4; r++) {
            obase[(size_t)r * H_ + ht * 16] = acc[ht][r] * inv[r];
        }
    }
}

extern "C" void kernel_launch(void* const* d_in, const int* in_sizes, int n_in,
                              void* d_out, int out_size, void* d_ws, size_t ws_size,
                              hipStream_t stream) {
    const float* x  = (const float*)d_in[0];
    const float* Wk = (const float*)d_in[1];
    const float* Wq = (const float*)d_in[2];
    const float* Wv = (const float*)d_in[3];
    float* out = (float*)d_out;

    __bf16* qb  = (__bf16*)d_ws;                       // [B][T][H] bf16
    __bf16* kb  = qb + (size_t)B_ * T_ * H_;           // [B][T][H] bf16
    __bf16* vTb = kb + (size_t)B_ * T_ * H_;           // [B][H][T] bf16

    proj_kernel<<<3072, 64, 0, stream>>>(x, Wq, Wk, Wv, qb, kb, vTb);
    attn_kernel<<<1024, 64, 0, stream>>>(qb, kb, vTb, out);
}

// Round 5
// 144.476 us; speedup vs baseline: 2.6717x; 2.6717x over previous
//
#include <hip/hip_runtime.h>
#include <hip/hip_bf16.h>

#define B_ 8
#define T_ 2048
#define C_ 1024
#define H_ 128
#define M_ (B_ * T_)          // 16384 rows
#define NSPLIT 4

typedef __bf16 bf16x8 __attribute__((ext_vector_type(8)));
typedef __bf16 bf16x4v __attribute__((ext_vector_type(4)));
typedef float f32x4 __attribute__((ext_vector_type(4)));

static __device__ __forceinline__ bf16x8 cvt8(float4 a, float4 b) {
    bf16x8 r;
    r[0] = (__bf16)a.x; r[1] = (__bf16)a.y; r[2] = (__bf16)a.z; r[3] = (__bf16)a.w;
    r[4] = (__bf16)b.x; r[5] = (__bf16)b.y; r[6] = (__bf16)b.z; r[7] = (__bf16)b.w;
    return r;
}

// ===========================================================================
// NEW PATH
// ===========================================================================

// ---------------------------------------------------------------------------
// Prep: fp32 -> bf16 for x (16.7M) and W q/k/v (3 x 131072), float4 loads.
// wb row layout: [0..127]=Wq, [128..255]=Wk, [256..383]=Wv.
// ---------------------------------------------------------------------------
__global__ __launch_bounds__(256) void prep_kernel(
    const float* __restrict__ x,
    const float* __restrict__ Wq, const float* __restrict__ Wk,
    const float* __restrict__ Wv,
    __bf16* __restrict__ xb, __bf16* __restrict__ wb)
{
    const int NX4 = M_ * C_ / 4;          // 4194304
    const int NW4 = 3 * (H_ * C_ / 4);    // 98304
    const int stride = gridDim.x * blockDim.x;
    for (int i = blockIdx.x * blockDim.x + threadIdx.x; i < NX4 + NW4; i += stride) {
        float4 v;
        __bf16* dst;
        if (i < NX4) {
            v = ((const float4*)x)[i];
            dst = xb + (size_t)i * 4;
        } else {
            int j = i - NX4;
            int w = j >> 15;               // 32768 float4 per matrix
            int jj = j & 32767;
            const float* s = (w == 0) ? Wq : (w == 1) ? Wk : Wv;
            v = ((const float4*)s)[jj];
            dst = wb + ((size_t)w << 17) + (size_t)jj * 4;
        }
        bf16x4v o;
        o[0] = (__bf16)v.x; o[1] = (__bf16)v.y; o[2] = (__bf16)v.z; o[3] = (__bf16)v.w;
        *(bf16x4v*)dst = o;
    }
}

// ---------------------------------------------------------------------------
// Projection GEMM (m97-structure): C[m][n] = xb[m][k] * wb[n][k], K=1024.
// 128x128 tile, BK=64, 256 threads = 4 waves, each wave 64x64 (4x4 frags).
// global_load_lds width-16 staging, linear LDS [128][64] bf16.
// blockIdx.y = which (0=q,1=k,2=v) selects wb row-block and output dest.
// ---------------------------------------------------------------------------
__global__ __launch_bounds__(256) void proj_gemm(
    const __bf16* __restrict__ xb, const __bf16* __restrict__ wb,
    __bf16* __restrict__ qb, __bf16* __restrict__ kb, __bf16* __restrict__ vTb)
{
    __shared__ __align__(16) __bf16 As[128 * 64];
    __shared__ __align__(16) __bf16 Bs[128 * 64];

    const int tid = threadIdx.x;
    const int lane = tid & 63;
    const int wid = tid >> 6;
    const int m0 = blockIdx.x * 128;
    const int which = blockIdx.y;
    const int n0 = which * 128;           // row offset into wb

    const int wr = wid >> 1, wc = wid & 1;
    const int fr = lane & 15;
    const int g4 = lane >> 4;
    const int koff8 = g4 * 8;
    const int rbase = g4 * 4;

    f32x4 acc[4][4];
#pragma unroll
    for (int i = 0; i < 4; i++)
#pragma unroll
        for (int j = 0; j < 4; j++) acc[i][j] = (f32x4){0.f, 0.f, 0.f, 0.f};

    for (int kt = 0; kt < C_ / 64; kt++) {
        const int k0 = kt * 64;
#pragma unroll
        for (int i = 0; i < 4; i++) {
            const int chunk = i * 256 + tid;
            const int r = chunk >> 3;
            const int c = (chunk & 7) * 8;
            const __bf16* ga = xb + (size_t)(m0 + r) * C_ + k0 + c;
            const __bf16* gb = wb + (size_t)(n0 + r) * C_ + k0 + c;
            __builtin_amdgcn_global_load_lds(
                (const __attribute__((address_space(1))) void*)ga,
                (__attribute__((address_space(3))) void*)&As[chunk * 8], 16, 0, 0);
            __builtin_amdgcn_global_load_lds(
                (const __attribute__((address_space(1))) void*)gb,
                (__attribute__((address_space(3))) void*)&Bs[chunk * 8], 16, 0, 0);
        }
        __syncthreads();
#pragma unroll
        for (int kk = 0; kk < 64; kk += 32) {
            bf16x8 ar[4], br[4];
#pragma unroll
            for (int i = 0; i < 4; i++)
                ar[i] = *(const bf16x8*)&As[(wr * 64 + i * 16 + fr) * 64 + kk + koff8];
#pragma unroll
            for (int j = 0; j < 4; j++)
                br[j] = *(const bf16x8*)&Bs[(wc * 64 + j * 16 + fr) * 64 + kk + koff8];
#pragma unroll
            for (int i = 0; i < 4; i++)
#pragma unroll
                for (int j = 0; j < 4; j++)
                    acc[i][j] = __builtin_amdgcn_mfma_f32_16x16x32_bf16(ar[i], br[j], acc[i][j], 0, 0, 0);
        }
        __syncthreads();
    }

    // Epilogue: D-layout col=lane&15, row=(lane>>4)*4+rr (m89-verified).
#pragma unroll
    for (int i = 0; i < 4; i++) {
#pragma unroll
        for (int j = 0; j < 4; j++) {
#pragma unroll
            for (int rr = 0; rr < 4; rr++) {
                const int row = m0 + wr * 64 + i * 16 + rbase + rr;   // b*T + t
                const int h = wc * 64 + j * 16 + fr;
                const __bf16 val = (__bf16)acc[i][j][rr];
                if (which == 0) {
                    qb[(size_t)row * H_ + h] = val;
                } else if (which == 1) {
                    kb[(size_t)row * H_ + h] = val;
                } else {
                    const int bb = row >> 11;
                    const int tt = row & (T_ - 1);
                    vTb[((size_t)bb * H_ + h) * T_ + tt] = val;
                }
            }
        }
    }
}

// ---------------------------------------------------------------------------
// Flash attention partial, causal, 4-way KV split. One wave per block; wave
// owns 16 q-rows and KV tiles [nk*s/4, nk*(s+1)/4). Writes unnormalized acc
// plus (m, l) stats to workspace. No __syncthreads (single-wave LDS deps are
// lgkmcnt-ordered by the compiler; avoids vmcnt(0) drains at barriers).
// ---------------------------------------------------------------------------
__global__ __launch_bounds__(64) void attn_part(
    const __bf16* __restrict__ qb, const __bf16* __restrict__ kb,
    const __bf16* __restrict__ vTb,
    float* __restrict__ acc_ws, float* __restrict__ m_ws, float* __restrict__ l_ws)
{
    __shared__ __align__(16) __bf16 plds[16][32];

    const int lane = threadIdx.x;
    const int gw = blockIdx.x;           // (b*128 + qt)*4 + s
    const int s = gw & 3;
    const int qt = (gw >> 2) & 127;
    const int b = gw >> 9;
    const int q0 = qt * 16;

    const int fr = lane & 15;
    const int koff = (lane >> 4) * 8;
    const int rbase = (lane >> 4) * 4;

    const __bf16* Qbase = qb + ((size_t)b * T_ + q0 + fr) * H_ + koff;
    bf16x8 qf[4];
#pragma unroll
    for (int hc = 0; hc < 4; hc++)
        qf[hc] = *(const bf16x8*)(Qbase + hc * 32);

    float m[4], l[4];
    f32x4 acc[8];
#pragma unroll
    for (int r = 0; r < 4; r++) { m[r] = -1e30f; l[r] = 0.f; }
#pragma unroll
    for (int i = 0; i < 8; i++) acc[i] = (f32x4){0.f, 0.f, 0.f, 0.f};

    const int nk = q0 / 32 + 1;          // 32-key tiles with k0 <= q0 (causal)
    const int lo = (nk * s) / NSPLIT;
    const int hi = (nk * (s + 1)) / NSPLIT;
    const float scale = 0.03125f;        // 1024^-0.5

    for (int kt = lo; kt < hi; kt++) {
        const int k0 = kt * 32;

        f32x4 s0 = (f32x4){0.f, 0.f, 0.f, 0.f};
        f32x4 s1 = (f32x4){0.f, 0.f, 0.f, 0.f};
        const __bf16* Kb0 = kb + ((size_t)b * T_ + k0 + fr) * H_ + koff;
        const __bf16* Kb1 = Kb0 + 16 * H_;
#pragma unroll
        for (int hc = 0; hc < 4; hc++) {
            bf16x8 kf0 = *(const bf16x8*)(Kb0 + hc * 32);
            s0 = __builtin_amdgcn_mfma_f32_16x16x32_bf16(qf[hc], kf0, s0, 0, 0, 0);
            bf16x8 kf1 = *(const bf16x8*)(Kb1 + hc * 32);
            s1 = __builtin_amdgcn_mfma_f32_16x16x32_bf16(qf[hc], kf1, s1, 0, 0, 0);
        }

#pragma unroll
        for (int r = 0; r < 4; r++) {
            const int qrow = q0 + rbase + r;
            float v0 = s0[r] * scale;
            float v1 = s1[r] * scale;
            if (k0 + fr > qrow)      v0 = -1e30f;
            if (k0 + 16 + fr > qrow) v1 = -1e30f;

            float mx = fmaxf(v0, v1);
#pragma unroll
            for (int d = 1; d < 16; d <<= 1) mx = fmaxf(mx, __shfl_xor(mx, d));
            const float mnew = fmaxf(m[r], mx);
            const float corr = __expf(m[r] - mnew);
            const float e0 = __expf(v0 - mnew);
            const float e1 = __expf(v1 - mnew);
            float rs = e0 + e1;
#pragma unroll
            for (int d = 1; d < 16; d <<= 1) rs += __shfl_xor(rs, d);
            l[r] = l[r] * corr + rs;
            m[r] = mnew;
#pragma unroll
            for (int ht = 0; ht < 8; ht++) acc[ht][r] *= corr;

            plds[rbase + r][fr] = (__bf16)e0;
            plds[rbase + r][16 + fr] = (__bf16)e1;
        }

        bf16x8 pa = *(const bf16x8*)(&plds[fr][koff]);

        const __bf16* Vb = vTb + ((size_t)b * H_ + fr) * T_ + k0 + koff;
#pragma unroll
        for (int ht = 0; ht < 8; ht++) {
            bf16x8 vf = *(const bf16x8*)(Vb + (size_t)ht * 16 * T_);
            acc[ht] = __builtin_amdgcn_mfma_f32_16x16x32_bf16(pa, vf, acc[ht], 0, 0, 0);
        }
    }

    // Write partials: acc_ws[s][g][col], m_ws/l_ws[s][g]; g = (b*128+qt)*16 + r.
    const int g0 = (b * 128 + qt) * 16;
#pragma unroll
    for (int ht = 0; ht < 8; ht++) {
#pragma unroll
        for (int r = 0; r < 4; r++) {
            acc_ws[((size_t)s * M_ + g0 + rbase + r) * H_ + ht * 16 + fr] = acc[ht][r];
        }
    }
    if (fr == 0) {
#pragma unroll
        for (int r = 0; r < 4; r++) {
            m_ws[(size_t)s * M_ + g0 + rbase + r] = m[r];
            l_ws[(size_t)s * M_ + g0 + rbase + r] = l[r];
        }
    }
}

// ---------------------------------------------------------------------------
// Merge: combine 4 partials per q-row, normalize, write fp32 out.
// One 64-lane block per (b,qt); lane handles 2 columns x 16 rows.
// ---------------------------------------------------------------------------
__global__ __launch_bounds__(64) void attn_merge(
    const float* __restrict__ acc_ws, const float* __restrict__ m_ws,
    const float* __restrict__ l_ws, float* __restrict__ out)
{
    const int lane = threadIdx.x;
    const int g0 = blockIdx.x * 16;
    for (int r = 0; r < 16; r++) {
        const int g = g0 + r;
        float mm = -1e30f, ms[NSPLIT];
#pragma unroll
        for (int s = 0; s < NSPLIT; s++) {
            ms[s] = m_ws[(size_t)s * M_ + g];
            mm = fmaxf(mm, ms[s]);
        }
        float ll = 0.f, sc[NSPLIT];
#pragma unroll
        for (int s = 0; s < NSPLIT; s++) {
            sc[s] = __expf(ms[s] - mm);
            ll += l_ws[(size_t)s * M_ + g] * sc[s];
        }
        const float inv = 1.0f / ll;
        float2 o = make_float2(0.f, 0.f);
#pragma unroll
        for (int s = 0; s < NSPLIT; s++) {
            float2 a = *(const float2*)&acc_ws[((size_t)s * M_ + g) * H_ + lane * 2];
            o.x += a.x * sc[s];
            o.y += a.y * sc[s];
        }
        o.x *= inv; o.y *= inv;
        *(float2*)&out[(size_t)g * H_ + lane * 2] = o;
    }
}

// ===========================================================================
// FALLBACK PATH (round-4 verified kernels; used only if ws_size is too small)
// ===========================================================================
__global__ __launch_bounds__(64) void proj_kernel(
    const float* __restrict__ x,
    const float* __restrict__ Wq, const float* __restrict__ Wk,
    const float* __restrict__ Wv,
    __bf16* __restrict__ qb, __bf16* __restrict__ kb, __bf16* __restrict__ vTb)
{
    const int lane = threadIdx.x;
    const int gw = blockIdx.x;
    const int which = gw >> 10;
    const int mt = gw & 1023;
    const float* W = (which == 0) ? Wq : (which == 1) ? Wk : Wv;
    const int fr = lane & 15;
    const int koff = (lane >> 4) * 8;
    const float* xrow = x + (size_t)(mt * 16 + fr) * C_ + koff;
    const float* wbase = W + (size_t)fr * C_ + koff;
    f32x4 acc[8];
#pragma unroll
    for (int i = 0; i < 8; i++) acc[i] = (f32x4){0.f, 0.f, 0.f, 0.f};
    for (int kc = 0; kc < C_; kc += 32) {
        float4 xa = *(const float4*)(xrow + kc);
        float4 xb2 = *(const float4*)(xrow + kc + 4);
        bf16x8 af = cvt8(xa, xb2);
#pragma unroll
        for (int ht = 0; ht < 8; ht++) {
            const float* wrow = wbase + (size_t)ht * 16 * C_ + kc;
            float4 wa = *(const float4*)(wrow);
            float4 wb2 = *(const float4*)(wrow + 4);
            bf16x8 bfr = cvt8(wa, wb2);
            acc[ht] = __builtin_amdgcn_mfma_f32_16x16x32_bf16(af, bfr, acc[ht], 0, 0, 0);
        }
    }
    const int rbase = (lane >> 4) * 4;
#pragma unroll
    for (int ht = 0; ht < 8; ht++) {
#pragma unroll
        for (int r = 0; r < 4; r++) {
            int row = mt * 16 + rbase + r;
            int h = ht * 16 + fr;
            __bf16 val = (__bf16)acc[ht][r];
            if (which == 0) qb[(size_t)row * H_ + h] = val;
            else if (which == 1) kb[(size_t)row * H_ + h] = val;
            else {
                int bb = row >> 11; int tt = row & (T_ - 1);
                vTb[((size_t)bb * H_ + h) * T_ + tt] = val;
            }
        }
    }
}

__global__ __launch_bounds__(64) void attn_kernel(
    const __bf16* __restrict__ qb, const __bf16* __restrict__ kb,
    const __bf16* __restrict__ vTb, float* __restrict__ out)
{
    __shared__ __align__(16) __bf16 plds[16][32];
    const int lane = threadIdx.x;
    const int gw = blockIdx.x;
    const int b = gw >> 7;
    const int qt = gw & 127;
    const int q0 = qt * 16;
    const int fr = lane & 15;
    const int koff = (lane >> 4) * 8;
    const int rbase = (lane >> 4) * 4;
    const __bf16* Qbase = qb + ((size_t)b * T_ + q0 + fr) * H_ + koff;
    bf16x8 qf[4];
#pragma unroll
    for (int hc = 0; hc < 4; hc++) qf[hc] = *(const bf16x8*)(Qbase + hc * 32);
    float m[4], l[4];
    f32x4 acc[8];
#pragma unroll
    for (int r = 0; r < 4; r++) { m[r] = -1e30f; l[r] = 0.f; }
#pragma unroll
    for (int i = 0; i < 8; i++) acc[i] = (f32x4){0.f, 0.f, 0.f, 0.f};
    const int nkt = (q0 + 15) / 32 + 1;
    const float scale = 0.03125f;
    for (int kt = 0; kt < nkt; kt++) {
        const int k0 = kt * 32;
        f32x4 s0 = (f32x4){0.f, 0.f, 0.f, 0.f};
        f32x4 s1 = (f32x4){0.f, 0.f, 0.f, 0.f};
        const __bf16* Kb0 = kb + ((size_t)b * T_ + k0 + fr) * H_ + koff;
        const __bf16* Kb1 = Kb0 + 16 * H_;
#pragma unroll
        for (int hc = 0; hc < 4; hc++) {
            bf16x8 kf0 = *(const bf16x8*)(Kb0 + hc * 32);
            s0 = __builtin_amdgcn_mfma_f32_16x16x32_bf16(qf[hc], kf0, s0, 0, 0, 0);
            bf16x8 kf1 = *(const bf16x8*)(Kb1 + hc * 32);
            s1 = __builtin_amdgcn_mfma_f32_16x16x32_bf16(qf[hc], kf1, s1, 0, 0, 0);
        }
#pragma unroll
        for (int r = 0; r < 4; r++) {
            const int qrow = q0 + rbase + r;
            float v0 = s0[r] * scale;
            float v1 = s1[r] * scale;
            if (k0 + fr > qrow)      v0 = -1e30f;
            if (k0 + 16 + fr > qrow) v1 = -1e30f;
            float mx = fmaxf(v0, v1);
#pragma unroll
            for (int d = 1; d < 16; d <<= 1) mx = fmaxf(mx, __shfl_xor(mx, d));
            const float mnew = fmaxf(m[r], mx);
            const float corr = __expf(m[r] - mnew);
            const float e0 = __expf(v0 - mnew);
            const float e1 = __expf(v1 - mnew);
            float rs = e0 + e1;
#pragma unroll
            for (int d = 1; d < 16; d <<= 1) rs += __shfl_xor(rs, d);
            l[r] = l[r] * corr + rs;
            m[r] = mnew;
#pragma unroll
            for (int ht = 0; ht < 8; ht++) acc[ht][r] *= corr;
            plds[rbase + r][fr] = (__bf16)e0;
            plds[rbase + r][16 + fr] = (__bf16)e1;
        }
        __syncthreads();
        bf16x8 pa = *(const bf16x8*)(&plds[fr][koff]);
        const __bf16* Vb = vTb + ((size_t)b * H_ + fr) * T_ + k0 + koff;
#pragma unroll
        for (int ht = 0; ht < 8; ht++) {
            bf16x8 vf = *(const bf16x8*)(Vb + (size_t)ht * 16 * T_);
            acc[ht] = __builtin_amdgcn_mfma_f32_16x16x32_bf16(pa, vf, acc[ht], 0, 0, 0);
        }
        __syncthreads();
    }
    float inv[4];
#pragma unroll
    for (int r = 0; r < 4; r++) inv[r] = 1.0f / l[r];
    float* obase = out + ((size_t)b * T_ + q0 + rbase) * H_ + fr;
#pragma unroll
    for (int ht = 0; ht < 8; ht++) {
#pragma unroll
        for (int r = 0; r < 4; r++) {
            obase[(size_t)r * H_ + ht * 16] = acc[ht][r] * inv[r];
        }
    }
}

// ===========================================================================
extern "C" void kernel_launch(void* const* d_in, const int* in_sizes, int n_in,
                              void* d_out, int out_size, void* d_ws, size_t ws_size,
                              hipStream_t stream) {
    const float* x  = (const float*)d_in[0];
    const float* Wk = (const float*)d_in[1];
    const float* Wq = (const float*)d_in[2];
    const float* Wv = (const float*)d_in[3];
    float* out = (float*)d_out;

    // Workspace layout (new path):
    //   [0)          xb   M*C bf16   = 33,554,432 B   (aliased by acc_ws after proj)
    //   [+33554432)  wb   384*C bf16 =    786,432 B
    //   [+34340864)  qb   M*H bf16   =  4,194,304 B
    //   [+38535168)  kb   M*H bf16   =  4,194,304 B
    //   [+42729472)  vTb  B*H*T bf16 =  4,194,304 B
    //   [+46923776)  m_ws 4*M f32    =    262,144 B
    //   [+47185920)  l_ws 4*M f32    =    262,144 B
    //   total 47,448,064 B
    const size_t NEED = 47448064;
    uint8_t* ws = (uint8_t*)d_ws;

    if (ws_size >= NEED) {
        __bf16* xb  = (__bf16*)ws;
        __bf16* wb  = (__bf16*)(ws + 33554432);
        __bf16* qb  = (__bf16*)(ws + 34340864);
        __bf16* kb  = (__bf16*)(ws + 38535168);
        __bf16* vTb = (__bf16*)(ws + 42729472);
        float*  m_ws = (float*)(ws + 46923776);
        float*  l_ws = (float*)(ws + 47185920);
        float*  acc_ws = (float*)ws;     // aliases xb (proj done reading it)

        prep_kernel<<<2048, 256, 0, stream>>>(x, Wq, Wk, Wv, xb, wb);
        proj_gemm<<<dim3(M_ / 128, 3), 256, 0, stream>>>(xb, wb, qb, kb, vTb);
        attn_part<<<B_ * 128 * NSPLIT, 64, 0, stream>>>(qb, kb, vTb, acc_ws, m_ws, l_ws);
        attn_merge<<<B_ * 128, 64, 0, stream>>>(acc_ws, m_ws, l_ws, out);
    } else {
        // Fallback: round-4 verified path (needs 12.6 MB)
        __bf16* qb  = (__bf16*)d_ws;
        __bf16* kb  = qb + (size_t)M_ * H_;
        __bf16* vTb = kb + (size_t)M_ * H_;
        proj_kernel<<<3072, 64, 0, stream>>>(x, Wq, Wk, Wv, qb, kb, vTb);
        attn_kernel<<<1024, 64, 0, stream>>>(qb, kb, vTb, out);
    }
}

// Round 7
// 124.383 us; speedup vs baseline: 3.1033x; 1.1615x over previous
//
#include <hip/hip_runtime.h>
#include <hip/hip_bf16.h>

#define B_ 8
#define T_ 2048
#define C_ 1024
#define H_ 128
#define M_ (B_ * T_)          // 16384 rows
#define NSPLIT 4

typedef __bf16 bf16x8 __attribute__((ext_vector_type(8)));
typedef __bf16 bf16x4v __attribute__((ext_vector_type(4)));
typedef float f32x4 __attribute__((ext_vector_type(4)));

static __device__ __forceinline__ bf16x8 cvt8(float4 a, float4 b) {
    bf16x8 r;
    r[0] = (__bf16)a.x; r[1] = (__bf16)a.y; r[2] = (__bf16)a.z; r[3] = (__bf16)a.w;
    r[4] = (__bf16)b.x; r[5] = (__bf16)b.y; r[6] = (__bf16)b.z; r[7] = (__bf16)b.w;
    return r;
}

// ===========================================================================
// MAIN PATH
// ===========================================================================

// ---------------------------------------------------------------------------
// Prep: fp32 -> bf16 for x (16.7M) and W q/k/v (3 x 131072), float4 loads.
// ---------------------------------------------------------------------------
__global__ __launch_bounds__(256) void prep_kernel(
    const float* __restrict__ x,
    const float* __restrict__ Wq, const float* __restrict__ Wk,
    const float* __restrict__ Wv,
    __bf16* __restrict__ xb, __bf16* __restrict__ wb)
{
    const int NX4 = M_ * C_ / 4;          // 4194304
    const int NW4 = 3 * (H_ * C_ / 4);    // 98304
    const int stride = gridDim.x * blockDim.x;
    for (int i = blockIdx.x * blockDim.x + threadIdx.x; i < NX4 + NW4; i += stride) {
        float4 v;
        __bf16* dst;
        if (i < NX4) {
            v = ((const float4*)x)[i];
            dst = xb + (size_t)i * 4;
        } else {
            int j = i - NX4;
            int w = j >> 15;
            int jj = j & 32767;
            const float* s = (w == 0) ? Wq : (w == 1) ? Wk : Wv;
            v = ((const float4*)s)[jj];
            dst = wb + ((size_t)w << 17) + (size_t)jj * 4;
        }
        bf16x4v o;
        o[0] = (__bf16)v.x; o[1] = (__bf16)v.y; o[2] = (__bf16)v.z; o[3] = (__bf16)v.w;
        *(bf16x4v*)dst = o;
    }
}

// ---------------------------------------------------------------------------
// Projection GEMM (m97-structure): 128x128 tile, BK=64, 4 waves.
// ---------------------------------------------------------------------------
__global__ __launch_bounds__(256) void proj_gemm(
    const __bf16* __restrict__ xb, const __bf16* __restrict__ wb,
    __bf16* __restrict__ qb, __bf16* __restrict__ kb, __bf16* __restrict__ vTb)
{
    __shared__ __align__(16) __bf16 As[128 * 64];
    __shared__ __align__(16) __bf16 Bs[128 * 64];

    const int tid = threadIdx.x;
    const int lane = tid & 63;
    const int wid = tid >> 6;
    const int m0 = blockIdx.x * 128;
    const int which = blockIdx.y;
    const int n0 = which * 128;

    const int wr = wid >> 1, wc = wid & 1;
    const int fr = lane & 15;
    const int g4 = lane >> 4;
    const int koff8 = g4 * 8;
    const int rbase = g4 * 4;

    f32x4 acc[4][4];
#pragma unroll
    for (int i = 0; i < 4; i++)
#pragma unroll
        for (int j = 0; j < 4; j++) acc[i][j] = (f32x4){0.f, 0.f, 0.f, 0.f};

    for (int kt = 0; kt < C_ / 64; kt++) {
        const int k0 = kt * 64;
#pragma unroll
        for (int i = 0; i < 4; i++) {
            const int chunk = i * 256 + tid;
            const int r = chunk >> 3;
            const int c = (chunk & 7) * 8;
            const __bf16* ga = xb + (size_t)(m0 + r) * C_ + k0 + c;
            const __bf16* gb = wb + (size_t)(n0 + r) * C_ + k0 + c;
            __builtin_amdgcn_global_load_lds(
                (const __attribute__((address_space(1))) void*)ga,
                (__attribute__((address_space(3))) void*)&As[chunk * 8], 16, 0, 0);
            __builtin_amdgcn_global_load_lds(
                (const __attribute__((address_space(1))) void*)gb,
                (__attribute__((address_space(3))) void*)&Bs[chunk * 8], 16, 0, 0);
        }
        __syncthreads();
#pragma unroll
        for (int kk = 0; kk < 64; kk += 32) {
            bf16x8 ar[4], br[4];
#pragma unroll
            for (int i = 0; i < 4; i++)
                ar[i] = *(const bf16x8*)&As[(wr * 64 + i * 16 + fr) * 64 + kk + koff8];
#pragma unroll
            for (int j = 0; j < 4; j++)
                br[j] = *(const bf16x8*)&Bs[(wc * 64 + j * 16 + fr) * 64 + kk + koff8];
#pragma unroll
            for (int i = 0; i < 4; i++)
#pragma unroll
                for (int j = 0; j < 4; j++)
                    acc[i][j] = __builtin_amdgcn_mfma_f32_16x16x32_bf16(ar[i], br[j], acc[i][j], 0, 0, 0);
        }
        __syncthreads();
    }

#pragma unroll
    for (int i = 0; i < 4; i++) {
#pragma unroll
        for (int j = 0; j < 4; j++) {
#pragma unroll
            for (int rr = 0; rr < 4; rr++) {
                const int row = m0 + wr * 64 + i * 16 + rbase + rr;
                const int h = wc * 64 + j * 16 + fr;
                const __bf16 val = (__bf16)acc[i][j][rr];
                if (which == 0) {
                    qb[(size_t)row * H_ + h] = val;
                } else if (which == 1) {
                    kb[(size_t)row * H_ + h] = val;
                } else {
                    const int bb = row >> 11;
                    const int tt = row & (T_ - 1);
                    vTb[((size_t)bb * H_ + h) * T_ + tt] = val;
                }
            }
        }
    }
}

// ---------------------------------------------------------------------------
// Flash attention partial, causal, 4-way KV split, QBLK=32.
// One wave per block; wave owns 32 q-rows (two 16-row groups) so K/V frag
// loads are amortized over 2x MFMAs and the two softmax chains give ILP.
// P LDS is double-buffered (kt parity) so the compiler can pipeline tile
// t+1's QK^T with tile t's PV. No __syncthreads (single wave).
// ---------------------------------------------------------------------------
__global__ __launch_bounds__(64, 2) void attn_part(
    const __bf16* __restrict__ qb, const __bf16* __restrict__ kb,
    const __bf16* __restrict__ vTb,
    float* __restrict__ acc_ws, float* __restrict__ m_ws, float* __restrict__ l_ws)
{
    __shared__ __align__(16) __bf16 plds[2][32][32];

    const int lane = threadIdx.x;
    const int gw = blockIdx.x;           // ((b*64 + qt)*4 + s), 2048 total
    const int s = gw & 3;
    const int qt = (gw >> 2) & 63;
    const int b = gw >> 8;
    const int q0 = qt * 32;

    const int fr = lane & 15;
    const int koff = (lane >> 4) * 8;
    const int rbase = (lane >> 4) * 4;

    // Q fragments: 2 row-groups x 4 K-chunks over H=128
    bf16x8 qf[2][4];
#pragma unroll
    for (int g = 0; g < 2; g++) {
        const __bf16* Qbase = qb + ((size_t)b * T_ + q0 + g * 16 + fr) * H_ + koff;
#pragma unroll
        for (int hc = 0; hc < 4; hc++)
            qf[g][hc] = *(const bf16x8*)(Qbase + hc * 32);
    }

    float m[2][4], l[2][4];
    f32x4 acc[2][8];
#pragma unroll
    for (int g = 0; g < 2; g++) {
#pragma unroll
        for (int r = 0; r < 4; r++) { m[g][r] = -1e30f; l[g][r] = 0.f; }
#pragma unroll
        for (int i = 0; i < 8; i++) acc[g][i] = (f32x4){0.f, 0.f, 0.f, 0.f};
    }

    const int nk = qt + 1;               // 32-key tiles with k0 <= q0 (causal)
    const int lo = (nk * s) / NSPLIT;
    const int hi = (nk * (s + 1)) / NSPLIT;
    const float scale = 0.03125f;        // 1024^-0.5

    for (int kt = lo; kt < hi; kt++) {
        const int k0 = kt * 32;
        const int pb = kt & 1;

        // --- S = Q K^T, both groups, 32 keys (two 16-key halves) ---
        f32x4 sg[2][2];
#pragma unroll
        for (int g = 0; g < 2; g++) {
            sg[g][0] = (f32x4){0.f, 0.f, 0.f, 0.f};
            sg[g][1] = (f32x4){0.f, 0.f, 0.f, 0.f};
        }
        const __bf16* Kb0 = kb + ((size_t)b * T_ + k0 + fr) * H_ + koff;
        const __bf16* Kb1 = Kb0 + 16 * H_;
#pragma unroll
        for (int hc = 0; hc < 4; hc++) {
            bf16x8 kf0 = *(const bf16x8*)(Kb0 + hc * 32);
            bf16x8 kf1 = *(const bf16x8*)(Kb1 + hc * 32);
#pragma unroll
            for (int g = 0; g < 2; g++) {
                sg[g][0] = __builtin_amdgcn_mfma_f32_16x16x32_bf16(qf[g][hc], kf0, sg[g][0], 0, 0, 0);
                sg[g][1] = __builtin_amdgcn_mfma_f32_16x16x32_bf16(qf[g][hc], kf1, sg[g][1], 0, 0, 0);
            }
        }

        // --- scale + mask + online softmax (fp32), independent per group ---
#pragma unroll
        for (int g = 0; g < 2; g++) {
#pragma unroll
            for (int r = 0; r < 4; r++) {
                const int qrow = q0 + g * 16 + rbase + r;
                float v0 = sg[g][0][r] * scale;
                float v1 = sg[g][1][r] * scale;
                if (k0 + fr > qrow)      v0 = -1e30f;
                if (k0 + 16 + fr > qrow) v1 = -1e30f;

                float mx = fmaxf(v0, v1);
#pragma unroll
                for (int d = 1; d < 16; d <<= 1) mx = fmaxf(mx, __shfl_xor(mx, d));
                const float mnew = fmaxf(m[g][r], mx);
                const float corr = __expf(m[g][r] - mnew);
                const float e0 = __expf(v0 - mnew);
                const float e1 = __expf(v1 - mnew);
                float rs = e0 + e1;
#pragma unroll
                for (int d = 1; d < 16; d <<= 1) rs += __shfl_xor(rs, d);
                l[g][r] = l[g][r] * corr + rs;
                m[g][r] = mnew;
#pragma unroll
                for (int ht = 0; ht < 8; ht++) acc[g][ht][r] *= corr;

                plds[pb][g * 16 + rbase + r][fr] = (__bf16)e0;
                plds[pb][g * 16 + rbase + r][16 + fr] = (__bf16)e1;
            }
        }

        // --- P A-frags ---
        bf16x8 pa[2];
#pragma unroll
        for (int g = 0; g < 2; g++)
            pa[g] = *(const bf16x8*)(&plds[pb][g * 16 + fr][koff]);

        // --- O += P V : V-frags shared by both groups ---
        const __bf16* Vb = vTb + ((size_t)b * H_ + fr) * T_ + k0 + koff;
#pragma unroll
        for (int ht = 0; ht < 8; ht++) {
            bf16x8 vf = *(const bf16x8*)(Vb + (size_t)ht * 16 * T_);
#pragma unroll
            for (int g = 0; g < 2; g++)
                acc[g][ht] = __builtin_amdgcn_mfma_f32_16x16x32_bf16(pa[g], vf, acc[g][ht], 0, 0, 0);
        }
    }

    // Write partials: acc_ws[s][row][col], m_ws/l_ws[s][row]; row = b*T + t.
#pragma unroll
    for (int g = 0; g < 2; g++) {
        const int row0 = b * T_ + q0 + g * 16;
#pragma unroll
        for (int ht = 0; ht < 8; ht++) {
#pragma unroll
            for (int r = 0; r < 4; r++) {
                acc_ws[((size_t)s * M_ + row0 + rbase + r) * H_ + ht * 16 + fr] = acc[g][ht][r];
            }
        }
        if (fr == 0) {
#pragma unroll
            for (int r = 0; r < 4; r++) {
                m_ws[(size_t)s * M_ + row0 + rbase + r] = m[g][r];
                l_ws[(size_t)s * M_ + row0 + rbase + r] = l[g][r];
            }
        }
    }
}

// ---------------------------------------------------------------------------
// Merge: combine 4 partials per q-row, normalize, write fp32 out.
// ---------------------------------------------------------------------------
__global__ __launch_bounds__(64) void attn_merge(
    const float* __restrict__ acc_ws, const float* __restrict__ m_ws,
    const float* __restrict__ l_ws, float* __restrict__ out)
{
    const int lane = threadIdx.x;
    const int g0 = blockIdx.x * 16;
    for (int r = 0; r < 16; r++) {
        const int g = g0 + r;
        float mm = -1e30f, ms[NSPLIT];
#pragma unroll
        for (int s = 0; s < NSPLIT; s++) {
            ms[s] = m_ws[(size_t)s * M_ + g];
            mm = fmaxf(mm, ms[s]);
        }
        float ll = 0.f, sc[NSPLIT];
#pragma unroll
        for (int s = 0; s < NSPLIT; s++) {
            sc[s] = __expf(ms[s] - mm);
            ll += l_ws[(size_t)s * M_ + g] * sc[s];
        }
        const float inv = 1.0f / ll;
        float2 o = make_float2(0.f, 0.f);
#pragma unroll
        for (int s = 0; s < NSPLIT; s++) {
            float2 a = *(const float2*)&acc_ws[((size_t)s * M_ + g) * H_ + lane * 2];
            o.x += a.x * sc[s];
            o.y += a.y * sc[s];
        }
        o.x *= inv; o.y *= inv;
        *(float2*)&out[(size_t)g * H_ + lane * 2] = o;
    }
}

// ===========================================================================
// FALLBACK PATH (round-4 verified; used only if ws_size too small)
// ===========================================================================
__global__ __launch_bounds__(64) void proj_kernel(
    const float* __restrict__ x,
    const float* __restrict__ Wq, const float* __restrict__ Wk,
    const float* __restrict__ Wv,
    __bf16* __restrict__ qb, __bf16* __restrict__ kb, __bf16* __restrict__ vTb)
{
    const int lane = threadIdx.x;
    const int gw = blockIdx.x;
    const int which = gw >> 10;
    const int mt = gw & 1023;
    const float* W = (which == 0) ? Wq : (which == 1) ? Wk : Wv;
    const int fr = lane & 15;
    const int koff = (lane >> 4) * 8;
    const float* xrow = x + (size_t)(mt * 16 + fr) * C_ + koff;
    const float* wbase = W + (size_t)fr * C_ + koff;
    f32x4 acc[8];
#pragma unroll
    for (int i = 0; i < 8; i++) acc[i] = (f32x4){0.f, 0.f, 0.f, 0.f};
    for (int kc = 0; kc < C_; kc += 32) {
        float4 xa = *(const float4*)(xrow + kc);
        float4 xb2 = *(const float4*)(xrow + kc + 4);
        bf16x8 af = cvt8(xa, xb2);
#pragma unroll
        for (int ht = 0; ht < 8; ht++) {
            const float* wrow = wbase + (size_t)ht * 16 * C_ + kc;
            float4 wa = *(const float4*)(wrow);
            float4 wb2 = *(const float4*)(wrow + 4);
            bf16x8 bfr = cvt8(wa, wb2);
            acc[ht] = __builtin_amdgcn_mfma_f32_16x16x32_bf16(af, bfr, acc[ht], 0, 0, 0);
        }
    }
    const int rbase = (lane >> 4) * 4;
#pragma unroll
    for (int ht = 0; ht < 8; ht++) {
#pragma unroll
        for (int r = 0; r < 4; r++) {
            int row = mt * 16 + rbase + r;
            int h = ht * 16 + fr;
            __bf16 val = (__bf16)acc[ht][r];
            if (which == 0) qb[(size_t)row * H_ + h] = val;
            else if (which == 1) kb[(size_t)row * H_ + h] = val;
            else {
                int bb = row >> 11; int tt = row & (T_ - 1);
                vTb[((size_t)bb * H_ + h) * T_ + tt] = val;
            }
        }
    }
}

__global__ __launch_bounds__(64) void attn_kernel(
    const __bf16* __restrict__ qb, const __bf16* __restrict__ kb,
    const __bf16* __restrict__ vTb, float* __restrict__ out)
{
    __shared__ __align__(16) __bf16 plds[16][32];
    const int lane = threadIdx.x;
    const int gw = blockIdx.x;
    const int b = gw >> 7;
    const int qt = gw & 127;
    const int q0 = qt * 16;
    const int fr = lane & 15;
    const int koff = (lane >> 4) * 8;
    const int rbase = (lane >> 4) * 4;
    const __bf16* Qbase = qb + ((size_t)b * T_ + q0 + fr) * H_ + koff;
    bf16x8 qf[4];
#pragma unroll
    for (int hc = 0; hc < 4; hc++) qf[hc] = *(const bf16x8*)(Qbase + hc * 32);
    float m[4], l[4];
    f32x4 acc[8];
#pragma unroll
    for (int r = 0; r < 4; r++) { m[r] = -1e30f; l[r] = 0.f; }
#pragma unroll
    for (int i = 0; i < 8; i++) acc[i] = (f32x4){0.f, 0.f, 0.f, 0.f};
    const int nkt = (q0 + 15) / 32 + 1;
    const float scale = 0.03125f;
    for (int kt = 0; kt < nkt; kt++) {
        const int k0 = kt * 32;
        f32x4 s0 = (f32x4){0.f, 0.f, 0.f, 0.f};
        f32x4 s1 = (f32x4){0.f, 0.f, 0.f, 0.f};
        const __bf16* Kb0 = kb + ((size_t)b * T_ + k0 + fr) * H_ + koff;
        const __bf16* Kb1 = Kb0 + 16 * H_;
#pragma unroll
        for (int hc = 0; hc < 4; hc++) {
            bf16x8 kf0 = *(const bf16x8*)(Kb0 + hc * 32);
            s0 = __builtin_amdgcn_mfma_f32_16x16x32_bf16(qf[hc], kf0, s0, 0, 0, 0);
            bf16x8 kf1 = *(const bf16x8*)(Kb1 + hc * 32);
            s1 = __builtin_amdgcn_mfma_f32_16x16x32_bf16(qf[hc], kf1, s1, 0, 0, 0);
        }
#pragma unroll
        for (int r = 0; r < 4; r++) {
            const int qrow = q0 + rbase + r;
            float v0 = s0[r] * scale;
            float v1 = s1[r] * scale;
            if (k0 + fr > qrow)      v0 = -1e30f;
            if (k0 + 16 + fr > qrow) v1 = -1e30f;
            float mx = fmaxf(v0, v1);
#pragma unroll
            for (int d = 1; d < 16; d <<= 1) mx = fmaxf(mx, __shfl_xor(mx, d));
            const float mnew = fmaxf(m[r], mx);
            const float corr = __expf(m[r] - mnew);
            const float e0 = __expf(v0 - mnew);
            const float e1 = __expf(v1 - mnew);
            float rs = e0 + e1;
#pragma unroll
            for (int d = 1; d < 16; d <<= 1) rs += __shfl_xor(rs, d);
            l[r] = l[r] * corr + rs;
            m[r] = mnew;
#pragma unroll
            for (int ht = 0; ht < 8; ht++) acc[ht][r] *= corr;
            plds[rbase + r][fr] = (__bf16)e0;
            plds[rbase + r][16 + fr] = (__bf16)e1;
        }
        __syncthreads();
        bf16x8 pa = *(const bf16x8*)(&plds[fr][koff]);
        const __bf16* Vb = vTb + ((size_t)b * H_ + fr) * T_ + k0 + koff;
#pragma unroll
        for (int ht = 0; ht < 8; ht++) {
            bf16x8 vf = *(const bf16x8*)(Vb + (size_t)ht * 16 * T_);
            acc[ht] = __builtin_amdgcn_mfma_f32_16x16x32_bf16(pa, vf, acc[ht], 0, 0, 0);
        }
        __syncthreads();
    }
    float inv[4];
#pragma unroll
    for (int r = 0; r < 4; r++) inv[r] = 1.0f / l[r];
    float* obase = out + ((size_t)b * T_ + q0 + rbase) * H_ + fr;
#pragma unroll
    for (int ht = 0; ht < 8; ht++) {
#pragma unroll
        for (int r = 0; r < 4; r++) {
            obase[(size_t)r * H_ + ht * 16] = acc[ht][r] * inv[r];
        }
    }
}

// ===========================================================================
extern "C" void kernel_launch(void* const* d_in, const int* in_sizes, int n_in,
                              void* d_out, int out_size, void* d_ws, size_t ws_size,
                              hipStream_t stream) {
    const float* x  = (const float*)d_in[0];
    const float* Wk = (const float*)d_in[1];
    const float* Wq = (const float*)d_in[2];
    const float* Wv = (const float*)d_in[3];
    float* out = (float*)d_out;

    // Workspace layout (main path):
    //   [0)          xb   M*C bf16   = 33,554,432 B   (aliased by acc_ws after proj)
    //   [+33554432)  wb   384*C bf16 =    786,432 B
    //   [+34340864)  qb   M*H bf16   =  4,194,304 B
    //   [+38535168)  kb   M*H bf16   =  4,194,304 B
    //   [+42729472)  vTb  B*H*T bf16 =  4,194,304 B
    //   [+46923776)  m_ws 4*M f32    =    262,144 B
    //   [+47185920)  l_ws 4*M f32    =    262,144 B
    const size_t NEED = 47448064;
    uint8_t* ws = (uint8_t*)d_ws;

    if (ws_size >= NEED) {
        __bf16* xb  = (__bf16*)ws;
        __bf16* wb  = (__bf16*)(ws + 33554432);
        __bf16* qb  = (__bf16*)(ws + 34340864);
        __bf16* kb  = (__bf16*)(ws + 38535168);
        __bf16* vTb = (__bf16*)(ws + 42729472);
        float*  m_ws = (float*)(ws + 46923776);
        float*  l_ws = (float*)(ws + 47185920);
        float*  acc_ws = (float*)ws;     // aliases xb (proj done reading it)

        prep_kernel<<<2048, 256, 0, stream>>>(x, Wq, Wk, Wv, xb, wb);
        proj_gemm<<<dim3(M_ / 128, 3), 256, 0, stream>>>(xb, wb, qb, kb, vTb);
        attn_part<<<B_ * 64 * NSPLIT, 64, 0, stream>>>(qb, kb, vTb, acc_ws, m_ws, l_ws);
        attn_merge<<<B_ * 128, 64, 0, stream>>>(acc_ws, m_ws, l_ws, out);
    } else {
        // Fallback: round-4 verified path (needs 12.6 MB)
        __bf16* qb  = (__bf16*)d_ws;
        __bf16* kb  = qb + (size_t)M_ * H_;
        __bf16* vTb = kb + (size_t)M_ * H_;
        proj_kernel<<<3072, 64, 0, stream>>>(x, Wq, Wk, Wv, qb, kb, vTb);
        attn_kernel<<<1024, 64, 0, stream>>>(qb, kb, vTb, out);
    }
}